// Round 7
// baseline (244.482 us; speedup 1.0000x reference)
//
#include <hip/hip_runtime.h>
#include <stdint.h>

// Super-ko filter for Go.
// Staging (per harness header: "integer -> const int*"; bool is integer-kind;
// verified by round-0/3/5 absmax forensics — comparison happens in bf16 space,
// which is where the 998244352 = bf16(1e9) came from, NOT from bf16 inputs):
//  0 legal_mask          (B,19,19)   bool -> int32 0/1
//  1 capture_stone_mask  (B,361,361) bool -> int32 0/1
//  2 current_player      (B,)        int32
//  3 zpos                (361,3)     int32
//  4 current_hash        (B,)        int32
//  5 hash_history        (B,3610)    int32
//  6 move_count          (B,)        int32
//  7 logits              (B,19,19)   float32
// Output: (B,19,19) float32

#define GO_B     256
#define GO_N2    361
#define GO_M     3610
#define GO_SLABB (GO_N2 * GO_N2 * 4)   // 521284 bytes per batch (int32 mask)
#define TBL      1024                  // LDS hash table slots (power of 2)
#define NTHR     1024

__global__ __launch_bounds__(NTHR)
void superko_kernel(const int*   __restrict__ legal,
                    const int*   __restrict__ cap,
                    const int*   __restrict__ player,
                    const int*   __restrict__ zpos,
                    const int*   __restrict__ chash,
                    const int*   __restrict__ hist,
                    const int*   __restrict__ mcount,
                    const float* __restrict__ logits,
                    float*       __restrict__ out)
{
    __shared__ uint32_t Dl[GO_N2];      // remove-opponent-stone delta per point
    __shared__ uint32_t capx[GO_N2];    // accumulated capture delta per candidate
    __shared__ uint32_t pd[GO_N2];      // place-stone delta per point
    __shared__ uint32_t thash[TBL];     // hash table: candidate hash
    __shared__ int      tidx[TBL];      // hash table: candidate index, -1 = empty
    __shared__ uint8_t  rep[GO_N2];     // repeat flag
    __shared__ uint8_t  leg[GO_N2];     // legal flag

    const int b   = blockIdx.x;
    const int tid = threadIdx.x;
    const int p   = player[b];          // 0 or 1

    // ---- phase 1: per-point Zobrist deltas + init ----
    for (int i = tid; i < GO_N2; i += NTHR) {
        uint32_t z0 = (uint32_t)zpos[i * 3 + 0];
        uint32_t zp = (uint32_t)zpos[i * 3 + 1 + p];     // own stone key
        uint32_t zo = (uint32_t)zpos[i * 3 + 2 - p];     // opponent stone key
        Dl[i]   = zo ^ z0;
        pd[i]   = z0 ^ zp;
        capx[i] = 0u;
        rep[i]  = 0u;
        leg[i]  = legal[(size_t)b * GO_N2 + i] != 0;
    }
    for (int s = tid; s < TBL; s += NTHR) tidx[s] = -1;
    __syncthreads();

    // ---- phase 2: stream the 521284-byte int32 capture slab, sparse XOR ----
    {
        uintptr_t p0   = (uintptr_t)cap + (size_t)b * GO_SLABB;
        uintptr_t a0   = p0 & ~(uintptr_t)15;            // 16B-aligned start
        const uint32_t lead   = (uint32_t)(p0 - a0);     // 0,4,8,12
        const uint32_t nchunk = (lead + GO_SLABB + 15u) >> 4;  // <= 32582
        const uint4* __restrict__ src = (const uint4*)a0;

        for (uint32_t cb = 0; cb < nchunk; cb += NTHR * 8u) {
            // batch up to 8 loads per thread for memory-level parallelism
            uint4    v[8];
            uint32_t cbase[8];
            int nv = 0;
            #pragma unroll
            for (int k = 0; k < 8; ++k) {
                uint32_t c = cb + (uint32_t)tid + (uint32_t)k * NTHR;
                if (c < nchunk) { v[nv] = src[c]; cbase[nv] = c * 16u - lead; ++nv; }
            }
            for (int q = 0; q < nv; ++q) {
                uint4 w = v[q];
                if ((w.x | w.y | w.z | w.w) == 0u) continue;   // ~92% of chunks
                uint32_t base = cbase[q];            // byte offset in slab (may wrap)
                uint32_t dw[4] = { w.x, w.y, w.z, w.w };
                #pragma unroll
                for (int d = 0; d < 4; ++d) {
                    if (dw[d] != 0u) {
                        uint32_t f = base + (uint32_t)(d * 4);  // byte offset
                        if (f < (uint32_t)GO_SLABB) {           // rejects wrap + tail
                            uint32_t e = f >> 2;                // element index
                            uint32_t i = e / 361u;
                            uint32_t j = e - i * 361u;
                            atomicXor(&capx[i], Dl[j]);
                        }
                    }
                }
            }
        }
    }
    __syncthreads();

    // ---- phase 3: candidate hashes -> LDS hash table (legal only) ----
    const uint32_t ch = (uint32_t)chash[b];
    for (int i = tid; i < GO_N2; i += NTHR) {
        uint32_t nh = ch ^ pd[i] ^ capx[i];
        if (leg[i]) {
            uint32_t s = nh & (TBL - 1);
            while (true) {
                int prev = atomicCAS(&tidx[s], -1, i);
                if (prev == -1) { thash[s] = nh; break; }
                s = (s + 1) & (TBL - 1);
            }
        }
    }
    __syncthreads();

    // ---- phase 4: scan valid history prefix, probe table ----
    const int mc = mcount[b];
    for (int m = tid; m < mc; m += NTHR) {
        uint32_t h = (uint32_t)hist[(size_t)b * GO_M + m];
        uint32_t s = h & (TBL - 1);
        while (tidx[s] != -1) {
            if (thash[s] == h) rep[tidx[s]] = 1u;
            s = (s + 1) & (TBL - 1);
        }
    }
    __syncthreads();

    // ---- phase 5: masked logits ----
    for (int i = tid; i < GO_N2; i += NTHR) {
        bool keep = leg[i] && !rep[i];
        out[(size_t)b * GO_N2 + i] =
            keep ? logits[(size_t)b * GO_N2 + i] : -1.0e9f;
    }
}

extern "C" void kernel_launch(void* const* d_in, const int* in_sizes, int n_in,
                              void* d_out, int out_size, void* d_ws, size_t ws_size,
                              hipStream_t stream) {
    const int*   legal  = (const int*)d_in[0];
    const int*   cap    = (const int*)d_in[1];
    const int*   player = (const int*)d_in[2];
    const int*   zpos   = (const int*)d_in[3];
    const int*   chash  = (const int*)d_in[4];
    const int*   hist   = (const int*)d_in[5];
    const int*   mcount = (const int*)d_in[6];
    const float* logits = (const float*)d_in[7];
    float*       outp   = (float*)d_out;

    superko_kernel<<<GO_B, NTHR, 0, stream>>>(legal, cap, player, zpos, chash,
                                              hist, mcount, logits, outp);
}

// Round 9
// 216.848 us; speedup vs baseline: 1.1274x; 1.1274x over previous
//
#include <hip/hip_runtime.h>
#include <stdint.h>

// Super-ko filter for Go.
// Staging: bool inputs are int32 0/1 (verified round 7: absmax 0.0).
//  0 legal_mask          (B,19,19)   int32 0/1
//  1 capture_stone_mask  (B,361,361) int32 0/1
//  2 current_player      (B,)        int32
//  3 zpos                (361,3)     int32
//  4 current_hash        (B,)        int32
//  5 hash_history        (B,3610)    int32
//  6 move_count          (B,)        int32
//  7 logits              (B,19,19)   float32
// Output: (B,19,19) float32
//
// Round-7 post-mortem: v[nv] runtime-index compaction spilled the load batch
// to scratch (VGPR_Count=28, WRITE_SIZE=130MB). This version uses static
// indices only (rule #20) so the 8-deep uint4 batch lives in VGPRs.

#define GO_B     256
#define GO_N2    361
#define GO_M     3610
#define GO_SLABB (GO_N2 * GO_N2 * 4)   // 521284 bytes per batch (int32 mask)
#define TBL      1024                  // LDS hash table slots (power of 2)
#define NTHR     1024
#define DEPTH    8

__global__ __launch_bounds__(NTHR)
void superko_kernel(const int*   __restrict__ legal,
                    const int*   __restrict__ cap,
                    const int*   __restrict__ player,
                    const int*   __restrict__ zpos,
                    const int*   __restrict__ chash,
                    const int*   __restrict__ hist,
                    const int*   __restrict__ mcount,
                    const float* __restrict__ logits,
                    float*       __restrict__ out)
{
    __shared__ uint32_t Dl[GO_N2];      // remove-opponent-stone delta per point
    __shared__ uint32_t capx[GO_N2];    // accumulated capture delta per candidate
    __shared__ uint32_t pd[GO_N2];      // place-stone delta per point
    __shared__ uint32_t thash[TBL];     // hash table: candidate hash
    __shared__ int      tidx[TBL];      // hash table: candidate index, -1 = empty
    __shared__ uint8_t  rep[GO_N2];     // repeat flag
    __shared__ uint8_t  leg[GO_N2];     // legal flag

    const int b   = blockIdx.x;
    const int tid = threadIdx.x;
    const int p   = player[b];          // 0 or 1

    // ---- phase 1: per-point Zobrist deltas + init ----
    for (int i = tid; i < GO_N2; i += NTHR) {
        uint32_t z0 = (uint32_t)zpos[i * 3 + 0];
        uint32_t zp = (uint32_t)zpos[i * 3 + 1 + p];     // own stone key
        uint32_t zo = (uint32_t)zpos[i * 3 + 2 - p];     // opponent stone key
        Dl[i]   = zo ^ z0;
        pd[i]   = z0 ^ zp;
        capx[i] = 0u;
        rep[i]  = 0u;
        leg[i]  = legal[(size_t)b * GO_N2 + i] != 0;
    }
    for (int s = tid; s < TBL; s += NTHR) tidx[s] = -1;
    __syncthreads();

    // ---- phase 2: stream the 521284-byte int32 capture slab, sparse XOR ----
    {
        uintptr_t p0   = (uintptr_t)cap + (size_t)b * GO_SLABB;
        uintptr_t a0   = p0 & ~(uintptr_t)15;            // 16B-aligned start
        const uint32_t lead   = (uint32_t)(p0 - a0);     // 0,4,8,12
        const uint32_t nchunk = (lead + GO_SLABB + 15u) >> 4;  // <= 32582
        const uint4* __restrict__ src = (const uint4*)a0;

        for (uint32_t cb = 0; cb < nchunk; cb += NTHR * DEPTH) {
            // Statically-indexed 8-deep load batch: stays in VGPRs.
            uint4 w[DEPTH];
            #pragma unroll
            for (int k = 0; k < DEPTH; ++k) {
                uint32_t c = cb + (uint32_t)tid + (uint32_t)k * NTHR;
                uint4 z; z.x = 0u; z.y = 0u; z.z = 0u; z.w = 0u;
                w[k] = (c < nchunk) ? src[c] : z;
            }
            #pragma unroll
            for (int k = 0; k < DEPTH; ++k) {
                uint4 ww = w[k];
                if ((ww.x | ww.y | ww.z | ww.w) == 0u) continue;  // ~92% of chunks
                uint32_t base = (cb + (uint32_t)tid + (uint32_t)k * NTHR) * 16u - lead;
                uint32_t dw[4] = { ww.x, ww.y, ww.z, ww.w };
                #pragma unroll
                for (int d = 0; d < 4; ++d) {
                    if (dw[d] != 0u) {
                        uint32_t f = base + (uint32_t)(d * 4);  // byte offset in slab
                        if (f < (uint32_t)GO_SLABB) {           // rejects lead-wrap + tail
                            uint32_t e = f >> 2;                // element index
                            uint32_t i = e / 361u;
                            uint32_t j = e - i * 361u;
                            atomicXor(&capx[i], Dl[j]);
                        }
                    }
                }
            }
        }
    }
    __syncthreads();

    // ---- phase 3: candidate hashes -> LDS hash table (legal only) ----
    const uint32_t ch = (uint32_t)chash[b];
    for (int i = tid; i < GO_N2; i += NTHR) {
        uint32_t nh = ch ^ pd[i] ^ capx[i];
        if (leg[i]) {
            uint32_t s = nh & (TBL - 1);
            while (true) {
                int prev = atomicCAS(&tidx[s], -1, i);
                if (prev == -1) { thash[s] = nh; break; }
                s = (s + 1) & (TBL - 1);
            }
        }
    }
    __syncthreads();

    // ---- phase 4: scan valid history prefix, probe table ----
    const int mc = mcount[b];
    for (int m = tid; m < mc; m += NTHR) {
        uint32_t h = (uint32_t)hist[(size_t)b * GO_M + m];
        uint32_t s = h & (TBL - 1);
        while (tidx[s] != -1) {
            if (thash[s] == h) rep[tidx[s]] = 1u;
            s = (s + 1) & (TBL - 1);
        }
    }
    __syncthreads();

    // ---- phase 5: masked logits ----
    for (int i = tid; i < GO_N2; i += NTHR) {
        bool keep = leg[i] && !rep[i];
        out[(size_t)b * GO_N2 + i] =
            keep ? logits[(size_t)b * GO_N2 + i] : -1.0e9f;
    }
}

extern "C" void kernel_launch(void* const* d_in, const int* in_sizes, int n_in,
                              void* d_out, int out_size, void* d_ws, size_t ws_size,
                              hipStream_t stream) {
    const int*   legal  = (const int*)d_in[0];
    const int*   cap    = (const int*)d_in[1];
    const int*   player = (const int*)d_in[2];
    const int*   zpos   = (const int*)d_in[3];
    const int*   chash  = (const int*)d_in[4];
    const int*   hist   = (const int*)d_in[5];
    const int*   mcount = (const int*)d_in[6];
    const float* logits = (const float*)d_in[7];
    float*       outp   = (float*)d_out;

    superko_kernel<<<GO_B, NTHR, 0, stream>>>(legal, cap, player, zpos, chash,
                                              hist, mcount, logits, outp);
}